// Round 1
// 184.974 us; speedup vs baseline: 1.0021x; 1.0021x over previous
//
#include <hip/hip_runtime.h>
#include <math.h>

#define CHI 64
#define CHO 64
#define HH 128
#define WW 128
#define NB 4
#define KK 9
#define NOFF 27
#define EPSV 1e-5f
#define PLANE (HH * WW)
#define SP 72                 // LDS ci-stride (bytes=144: 16B-aligned, b128 2-way=free)

typedef float v2f __attribute__((ext_vector_type(2)));
typedef float f2v __attribute__((ext_vector_type(2), aligned(4)));
typedef float f32x4 __attribute__((ext_vector_type(4)));
typedef short bf16x8 __attribute__((ext_vector_type(8)));

__device__ __forceinline__ v2f pkfma(v2f a, v2f b, v2f c) {
#if __has_builtin(__builtin_elementwise_fma)
    return __builtin_elementwise_fma(a, b, c);
#else
    return a * b + c;
#endif
}

// fp32 -> bf16 round-to-nearest-even
__device__ __forceinline__ unsigned short f2bf(float f) {
    unsigned u = __float_as_uint(f);
    u += 0x7fff + ((u >> 16) & 1);
    return (unsigned short)(u >> 16);
}

// ---------------- prep: pack MFMA A-fragment tables (bf16) ----------------
__global__ __launch_bounds__(256) void prep_kernel(const float* __restrict__ w,
                                                   const float* __restrict__ w_off,
                                                   unsigned short* __restrict__ w_bf,
                                                   unsigned short* __restrict__ woA) {
    int i = blockIdx.x * 256 + threadIdx.x;    // grid 144*256 = 36864 exactly
    {
        int j    = i & 7;
        int lane = (i >> 3) & 63;
        int ks   = (i >> 9) & 1;
        int ct   = (i >> 10) & 3;
        int kk   = i >> 12;                    // 0..8
        int co   = ct * 16 + (lane & 15);
        int ci   = ks * 32 + ((lane >> 4) & 3) * 8 + j;
        w_bf[i]  = f2bf(w[(co * CHI + ci) * KK + kk]);
    }
    if (i < 18432) {
        int j    = i & 7;
        int lane = (i >> 3) & 63;
        int ct   = (i >> 9) & 1;
        int ks   = (i >> 10) & 1;
        int kk   = i >> 11;                    // 0..8
        int c    = ct * 16 + (lane & 15);
        int ci   = ks * 32 + (lane >> 4) * 8 + j;
        woA[i]   = (c < NOFF) ? f2bf(w_off[(c * CHI + ci) * KK + kk]) : (unsigned short)0;
    }
}

// ---------------- offset conv via MFMA (unchanged) ----------------
__global__ __launch_bounds__(256) void off_conv_kernel(const float* __restrict__ x,
                                                       const unsigned short* __restrict__ woA,
                                                       float* __restrict__ off) {
    const int id    = blockIdx.x;
    const int slot  = id & 7;
    const int b     = slot >> 1;
    const int rb    = id >> 3;                 // 0..127
    const int h     = (slot & 1) * 64 + (rb >> 1);
    const int whalf = rb & 1;
    const int w0    = whalf * 64;
    const int tid   = threadIdx.x;
    const int lane  = tid & 63;
    const int wv    = __builtin_amdgcn_readfirstlane(tid >> 6);

    __shared__ __align__(16) unsigned short xs[3 * 66 * SP];     // 28512 B

    {
        const int px4 = (lane & 15) * 4;
        const int cio = lane >> 4;
#pragma unroll 3
        for (int it = 0; it < 12; it++) {
            int g  = it * 4 + wv;              // 0..47
            int ky = g >> 4;
            int ci = (g & 15) * 4 + cio;
            int hr = h - 1 + ky;
            bool rok = (unsigned)hr < HH;
            const float* base = x + (((size_t)b * CHI + ci) * HH + (rok ? hr : 0)) * WW + w0 + px4;
            float4 v = rok ? *(const float4*)base : make_float4(0.f, 0.f, 0.f, 0.f);
            unsigned short* d = &xs[(ky * 66 + px4 + 1) * SP + ci];
            d[0]        = f2bf(v.x);
            d[SP]       = f2bf(v.y);
            d[2 * SP]   = f2bf(v.z);
            d[3 * SP]   = f2bf(v.w);
        }
    }
    for (int t = tid; t < 384; t += 256) {
        int ky = t >> 7, ci = (t >> 1) & 63, side = t & 1;
        int hr = h - 1 + ky;
        int wc = w0 - 1 + side * 65;
        bool ok = ((unsigned)hr < HH) && ((unsigned)wc < WW);
        float v = ok ? x[(((size_t)b * CHI + ci) * HH + (ok ? hr : 0)) * WW + (ok ? wc : 0)] : 0.f;
        xs[(ky * 66 + side * 65) * SP + ci] = f2bf(v);
    }
    __syncthreads();

    const int quad = lane >> 4, pxin = lane & 15;
    f32x4 acc0 = {0.f, 0.f, 0.f, 0.f};
    f32x4 acc1 = {0.f, 0.f, 0.f, 0.f};

#pragma unroll 3
    for (int kk = 0; kk < KK; kk++) {
        const int ky = kk / 3, kx = kk - ky * 3;
#pragma unroll
        for (int ks = 0; ks < 2; ks++) {
            const bf16x8* wa = (const bf16x8*)woA + (size_t)((kk * 2 + ks) * 2) * 64;
            bf16x8 A0 = wa[lane];
            bf16x8 A1 = wa[64 + lane];
            bf16x8 B = *(const bf16x8*)&xs[(ky * 66 + wv * 16 + pxin + kx) * SP
                                           + ks * 32 + quad * 8];
            acc0 = __builtin_amdgcn_mfma_f32_16x16x32_bf16(A0, B, acc0, 0, 0, 0);
            acc1 = __builtin_amdgcn_mfma_f32_16x16x32_bf16(A1, B, acc1, 0, 0, 0);
        }
    }

    float* outp = off + ((size_t)b * NOFF * HH + h) * WW + w0 + wv * 16 + pxin;
#pragma unroll
    for (int r = 0; r < 4; r++) {
        int c0 = quad * 4 + r;
        outp[c0 * PLANE] = acc0[r];
        int c1 = 16 + quad * 4 + r;
        if (c1 < NOFF) outp[c1 * PLANE] = acc1[r];
    }
}

// ---------------- deform sample + MFMA main conv ----------------
// R13: software-pipelined gathers. Per kk: all 32 bilinear gather loads are
// batched into registers and issued for kk+1 BEFORE the barrier of kk, so
// their L2 latency hides under barrier+ds_read+MFMA of kk. LDS exchange is
// double-buffered -> ONE raw s_barrier per kk (lgkmcnt drain only, NO vmcnt
// drain -- __syncthreads would drain the in-flight gathers and kill the
// pipeline). Offset loads prefetched 2 kk ahead; A-fragments issued before
// the gather batch (vmcnt is in-order: A must be older than gathers).
struct SampP { unsigned o0, o1; v2f cA, cB; };

__global__ __launch_bounds__(256, 3) void deform_kernel(const float* __restrict__ x,
                                                        const unsigned short* __restrict__ w_bf,
                                                        const float* __restrict__ off,
                                                        const float* __restrict__ b_off,
                                                        float* __restrict__ out,
                                                        float* __restrict__ part0,
                                                        int split) {
    const int id    = blockIdx.x;
    const int slot  = id & 7;
    const int b     = slot >> 1;
    int rb, klo, khi;
    float* dest;
    if (split) {
        int v = (id >> 3) & 1;
        rb  = id >> 4;                         // 0..127
        klo = v ? 4 : 0;
        khi = v ? 9 : 4;
        dest = v ? out : part0;
    } else {
        rb  = id >> 3;
        klo = 0; khi = 9;
        dest = out;
    }
    const int h     = (slot & 1) * 64 + (rb >> 1);
    const int whalf = rb & 1;
    const int tid   = threadIdx.x;
    const int lane  = tid & 63;

    const int pxs      = tid & 63;
    const int cig      = __builtin_amdgcn_readfirstlane(tid >> 6);
    const int pxin_s   = pxs & 15, pxtile_s = pxs >> 4;
    const int wave  = cig;
    const int quadc = lane >> 4, pxinc = lane & 15;
    const int colc  = pxinc ^ quadc;

    __shared__ __align__(16) unsigned short vbuf[2][4096];   // 16 KB, double-buffered

    f32x4 acc[4];
#pragma unroll
    for (int t = 0; t < 4; t++) acc[t] = (f32x4){0.f, 0.f, 0.f, 0.f};

    const float* xb   = x + ((size_t)b * CHI + cig * 16) * PLANE;
    const float* offb = off + (size_t)b * NOFF * PLANE + h * WW + whalf * 64 + pxs;
    const int w = whalf * 64 + pxs;

    auto ldoff = [&](int kk, float& dy, float& dx, float& mo) {
        dy = offb[(2 * kk) * PLANE]     + b_off[2 * kk];
        dx = offb[(2 * kk + 1) * PLANE] + b_off[2 * kk + 1];
        mo = offb[(18 + kk) * PLANE]    + b_off[18 + kk];
    };

    auto mkparams = [&](int kk, float dy, float dx, float mo) -> SampP {
        const int ky = kk / 3, kx = kk - ky * 3;
        float m  = 1.f / (1.f + __expf(-mo));
        float py  = (float)(h - 1 + ky) + dy;
        float px_ = (float)(w - 1 + kx) + dx;
        float fy0 = floorf(py), fx0 = floorf(px_);
        float wy = py - fy0, wx = px_ - fx0;
        int y0 = (int)fy0, x0 = (int)fx0;
        int y1 = y0 + 1, x1 = x0 + 1;
        bool vy0 = (unsigned)y0 < HH, vy1 = (unsigned)y1 < HH;
        bool vx0 = (unsigned)x0 < WW, vx1 = (unsigned)x1 < WW;
        float a00 = (vy0 && vx0) ? (1.f - wy) * (1.f - wx) * m : 0.f;
        float a01 = (vy0 && vx1) ? (1.f - wy) * wx * m : 0.f;
        float a10 = (vy1 && vx0) ? wy * (1.f - wx) * m : 0.f;
        float a11 = (vy1 && vx1) ? wy * wx * m : 0.f;

        int xbc = min(max(x0, 0), WW - 2);
        bool sel = (x0 == xbc);
        SampP sp;
        sp.cA = (v2f){ sel ? a00 : a01, sel ? a01 : a00 };
        sp.cB = (v2f){ sel ? a10 : a11, sel ? a11 : a10 };
        int cy0 = min(max(y0, 0), HH - 1), cy1 = min(max(y1, 0), HH - 1);
        sp.o0 = (unsigned)(cy0 * WW + xbc);
        sp.o1 = (unsigned)(cy1 * WW + xbc);
        return sp;
    };

    auto issue = [&](const SampP& sp, f2v (&p0)[16], f2v (&p1)[16]) {
        const float* pl = xb;
#pragma unroll
        for (int j = 0; j < 16; j++) {
            p0[j] = *(const f2v*)(pl + sp.o0);
            p1[j] = *(const f2v*)(pl + sp.o1);
            pl += PLANE;
        }
    };

    auto combine_write = [&](int cur, const SampP& sp,
                             const f2v (&p0)[16], const f2v (&p1)[16]) {
        bf16x8* vals = (bf16x8*)vbuf[cur];
#pragma unroll
        for (int gg = 0; gg < 2; gg++) {
            bf16x8 tmp;
#pragma unroll
            for (int j = 0; j < 8; j++) {
                v2f t = pkfma((v2f)p1[gg * 8 + j], sp.cB, (v2f)p0[gg * 8 + j] * sp.cA);
                tmp[j] = (short)f2bf(t.x + t.y);
            }
            int quad = ((cig & 1) << 1) | gg;
            int ks   = cig >> 1;
            vals[(pxtile_s * 2 + ks) * 64 + (quad << 4) + (pxin_s ^ quad)] = tmp;
        }
    };

    // prologue: offsets+params+gathers for klo; prefetch offsets for klo+1
    float dyn, dxn, mon;
    SampP spc;
    f2v p0[16], p1[16];
    ldoff(klo, dyn, dxn, mon);
    spc = mkparams(klo, dyn, dxn, mon);
    issue(spc, p0, p1);
    if (klo + 1 < khi) ldoff(klo + 1, dyn, dxn, mon);

    int cur = 0;
#pragma unroll 1
    for (int kk = klo; kk < khi; kk++) {
        // consume gathers(kk) -> LDS vals[cur]  (vmcnt waits inserted here)
        combine_write(cur, spc, p0, p1);

        // A-fragments for kk: issued BEFORE the gather batch for kk+1 so the
        // post-barrier vmcnt wait on A leaves the gathers in flight.
        const bf16x8* wb = (const bf16x8*)w_bf + (size_t)((kk * 4 + wave) * 2) * 64;
        bf16x8 A0 = wb[lane];
        bf16x8 A1 = wb[64 + lane];

        if (kk + 1 < khi) {
            spc = mkparams(kk + 1, dyn, dxn, mon);
            issue(spc, p0, p1);                         // 32 loads in flight across barrier
            if (kk + 2 < khi) ldoff(kk + 2, dyn, dxn, mon);
        }

        // LDS-visibility-only barrier: drain ds_writes, keep global loads in flight.
        asm volatile("s_waitcnt lgkmcnt(0)" ::: "memory");
        __builtin_amdgcn_s_barrier();
        __builtin_amdgcn_sched_barrier(0);

        const bf16x8* vals = (const bf16x8*)vbuf[cur];
#pragma unroll
        for (int t = 0; t < 4; t++) {
            bf16x8 B0 = vals[(t * 2 + 0) * 64 + (quadc << 4) + colc];
            bf16x8 B1 = vals[(t * 2 + 1) * 64 + (quadc << 4) + colc];
            acc[t] = __builtin_amdgcn_mfma_f32_16x16x32_bf16(A0, B0, acc[t], 0, 0, 0);
            acc[t] = __builtin_amdgcn_mfma_f32_16x16x32_bf16(A1, B1, acc[t], 0, 0, 0);
        }
        cur ^= 1;
        // note: writes to vals[cur^1] next iter are WAR-safe: the only readers
        // of that buffer ran before THIS iteration's barrier (program order).
    }

    // epilogue: raw partial write (bias deferred to stats/bn)
#pragma unroll
    for (int t = 0; t < 4; t++) {
#pragma unroll
        for (int r = 0; r < 4; r++) {
            int co = wave * 16 + quadc * 4 + r;
            dest[(((size_t)b * CHO + co) * HH + h) * WW + whalf * 64 + t * 16 + pxinc] =
                acc[t][r];
        }
    }
}

// ---------------- per-channel stats: y = part0 + out(+bias) ----------------
__global__ __launch_bounds__(256) void stats_kernel(const float* __restrict__ y1,
                                                    const float* __restrict__ part0,
                                                    const float* __restrict__ bias,
                                                    float* __restrict__ stats,
                                                    int split) {
    const int co  = blockIdx.x & 63;
    const int b   = (blockIdx.x >> 6) & 3;
    const int seg = blockIdx.x >> 8;           // 0..3
    const size_t base = ((size_t)b * CHO + co) * PLANE + seg * (PLANE / 4);
    const float bi = bias[co];
    const float4* p1 = (const float4*)(y1 + base);
    const float4* p0 = (const float4*)(part0 + base);
    float s = 0.f, s2 = 0.f;
    for (int i = threadIdx.x; i < PLANE / 16; i += 256) {
        float4 v = p1[i];
        if (split) {
            float4 u = p0[i];
            v.x += u.x; v.y += u.y; v.z += u.z; v.w += u.w;
        }
        v.x += bi; v.y += bi; v.z += bi; v.w += bi;
        s  += v.x + v.y + v.z + v.w;
        s2 += v.x * v.x + v.y * v.y + v.z * v.z + v.w * v.w;
    }
#pragma unroll
    for (int o = 32; o > 0; o >>= 1) {
        s  += __shfl_down(s, o, 64);
        s2 += __shfl_down(s2, o, 64);
    }
    __shared__ float ls[4], ls2[4];
    int lane = threadIdx.x & 63, wvv = threadIdx.x >> 6;
    if (lane == 0) { ls[wvv] = s; ls2[wvv] = s2; }
    __syncthreads();
    if (threadIdx.x == 0) {
        float ts = 0.f, t2 = 0.f;
#pragma unroll
        for (int i = 0; i < 4; i++) { ts += ls[i]; t2 += ls2[i]; }
        atomicAdd(&stats[co], ts);
        atomicAdd(&stats[64 + co], t2);
    }
}

// ---------------- BN + ReLU: y = part0 + out + bias, normalize, write out ---
__global__ __launch_bounds__(256) void bn_kernel(float* __restrict__ y,
                                                 const float* __restrict__ part0,
                                                 const float* __restrict__ bias,
                                                 const float* __restrict__ stats,
                                                 const float* __restrict__ gamma,
                                                 const float* __restrict__ beta,
                                                 int split) {
    size_t base = (size_t)blockIdx.x * 1024;
    int co = (int)((base >> 14) & 63);
    const float inv_n = 1.f / 65536.f;
    float mean = stats[co] * inv_n;
    float var  = stats[64 + co] * inv_n - mean * mean;
    float sc = gamma[co] * rsqrtf(var + EPSV);
    float sh = beta[co] - mean * sc;
    sh += bias[co] * sc;                       // fold bias into shift
    float4* p = (float4*)(y + base);
    float4 v = p[threadIdx.x];
    if (split) {
        float4 u = ((const float4*)(part0 + base))[threadIdx.x];
        v.x += u.x; v.y += u.y; v.z += u.z; v.w += u.w;
    }
    v.x = fmaxf(fmaf(v.x, sc, sh), 0.f);
    v.y = fmaxf(fmaf(v.y, sc, sh), 0.f);
    v.z = fmaxf(fmaf(v.z, sc, sh), 0.f);
    v.w = fmaxf(fmaf(v.w, sc, sh), 0.f);
    p[threadIdx.x] = v;
}

extern "C" void kernel_launch(void* const* d_in, const int* in_sizes, int n_in,
                              void* d_out, int out_size, void* d_ws, size_t ws_size,
                              hipStream_t stream) {
    const float* x     = (const float*)d_in[0];
    const float* w_off = (const float*)d_in[1];
    const float* b_off = (const float*)d_in[2];
    const float* wmat  = (const float*)d_in[3];
    const float* bvec  = (const float*)d_in[4];
    const float* gamma = (const float*)d_in[5];
    const float* beta  = (const float*)d_in[6];
    float* out = (float*)d_out;

    char* ws = (char*)d_ws;
    float* stats          = (float*)ws;                   // 512 B
    unsigned short* w_bf  = (unsigned short*)(ws + 1024); // 73728 B
    unsigned short* woA   = (unsigned short*)(ws + 74752);// 36864 B
    float* off            = (float*)(ws + 139264);        // 7077888 B
    float* part0          = (float*)(ws + 7217152);       // 16777216 B
    const size_t need = 7217152 + 16777216;
    const int split = (ws_size >= need) ? 1 : 0;

    hipMemsetAsync(stats, 0, 512, stream);
    prep_kernel<<<144, 256, 0, stream>>>(wmat, w_off, w_bf, woA);
    off_conv_kernel<<<1024, 256, 0, stream>>>(x, woA, off);
    deform_kernel<<<split ? 2048 : 1024, 256, 0, stream>>>(x, w_bf, off, b_off,
                                                           out, part0, split);
    stats_kernel<<<1024, 256, 0, stream>>>(out, part0, bvec, stats, split);
    bn_kernel<<<4096, 256, 0, stream>>>(out, part0, bvec, stats, gamma, beta, split);
}

// Round 2
// 174.917 us; speedup vs baseline: 1.0597x; 1.0575x over previous
//
#include <hip/hip_runtime.h>
#include <math.h>

#define CHI 64
#define CHO 64
#define HH 128
#define WW 128
#define NB 4
#define KK 9
#define NOFF 27
#define EPSV 1e-5f
#define PLANE (HH * WW)
#define SP 72                 // LDS ci-stride for off_conv staging

typedef float v2f __attribute__((ext_vector_type(2)));
typedef float f2v __attribute__((ext_vector_type(2), aligned(4)));
typedef float f32x4 __attribute__((ext_vector_type(4)));
typedef short bf16x8 __attribute__((ext_vector_type(8)));

__device__ __forceinline__ v2f pkfma(v2f a, v2f b, v2f c) {
#if __has_builtin(__builtin_elementwise_fma)
    return __builtin_elementwise_fma(a, b, c);
#else
    return a * b + c;
#endif
}

// fp32 -> bf16 round-to-nearest-even
__device__ __forceinline__ unsigned short f2bf(float f) {
    unsigned u = __float_as_uint(f);
    u += 0x7fff + ((u >> 16) & 1);
    return (unsigned short)(u >> 16);
}

// ---------------- prep: pack MFMA A-fragment tables (bf16) ----------------
__global__ __launch_bounds__(256) void prep_kernel(const float* __restrict__ w,
                                                   const float* __restrict__ w_off,
                                                   unsigned short* __restrict__ w_bf,
                                                   unsigned short* __restrict__ woA) {
    int i = blockIdx.x * 256 + threadIdx.x;    // grid 144*256 = 36864 exactly
    {
        int j    = i & 7;
        int lane = (i >> 3) & 63;
        int ks   = (i >> 9) & 1;
        int ct   = (i >> 10) & 3;
        int kk   = i >> 12;                    // 0..8
        int co   = ct * 16 + (lane & 15);
        int ci   = ks * 32 + ((lane >> 4) & 3) * 8 + j;
        w_bf[i]  = f2bf(w[(co * CHI + ci) * KK + kk]);
    }
    if (i < 18432) {
        int j    = i & 7;
        int lane = (i >> 3) & 63;
        int ct   = (i >> 9) & 1;
        int ks   = (i >> 10) & 1;
        int kk   = i >> 11;                    // 0..8
        int c    = ct * 16 + (lane & 15);
        int ci   = ks * 32 + (lane >> 4) * 8 + j;
        woA[i]   = (c < NOFF) ? f2bf(w_off[(c * CHI + ci) * KK + kk]) : (unsigned short)0;
    }
}

// ---------------- offset conv via MFMA (unchanged) ----------------
__global__ __launch_bounds__(256) void off_conv_kernel(const float* __restrict__ x,
                                                       const unsigned short* __restrict__ woA,
                                                       float* __restrict__ off) {
    const int id    = blockIdx.x;
    const int slot  = id & 7;
    const int b     = slot >> 1;
    const int rb    = id >> 3;                 // 0..127
    const int h     = (slot & 1) * 64 + (rb >> 1);
    const int whalf = rb & 1;
    const int w0    = whalf * 64;
    const int tid   = threadIdx.x;
    const int lane  = tid & 63;
    const int wv    = __builtin_amdgcn_readfirstlane(tid >> 6);

    __shared__ __align__(16) unsigned short xs[3 * 66 * SP];     // 28512 B

    {
        const int px4 = (lane & 15) * 4;
        const int cio = lane >> 4;
#pragma unroll 3
        for (int it = 0; it < 12; it++) {
            int g  = it * 4 + wv;              // 0..47
            int ky = g >> 4;
            int ci = (g & 15) * 4 + cio;
            int hr = h - 1 + ky;
            bool rok = (unsigned)hr < HH;
            const float* base = x + (((size_t)b * CHI + ci) * HH + (rok ? hr : 0)) * WW + w0 + px4;
            float4 v = rok ? *(const float4*)base : make_float4(0.f, 0.f, 0.f, 0.f);
            unsigned short* d = &xs[(ky * 66 + px4 + 1) * SP + ci];
            d[0]        = f2bf(v.x);
            d[SP]       = f2bf(v.y);
            d[2 * SP]   = f2bf(v.z);
            d[3 * SP]   = f2bf(v.w);
        }
    }
    for (int t = tid; t < 384; t += 256) {
        int ky = t >> 7, ci = (t >> 1) & 63, side = t & 1;
        int hr = h - 1 + ky;
        int wc = w0 - 1 + side * 65;
        bool ok = ((unsigned)hr < HH) && ((unsigned)wc < WW);
        float v = ok ? x[(((size_t)b * CHI + ci) * HH + (ok ? hr : 0)) * WW + (ok ? wc : 0)] : 0.f;
        xs[(ky * 66 + side * 65) * SP + ci] = f2bf(v);
    }
    __syncthreads();

    const int quad = lane >> 4, pxin = lane & 15;
    f32x4 acc0 = {0.f, 0.f, 0.f, 0.f};
    f32x4 acc1 = {0.f, 0.f, 0.f, 0.f};

#pragma unroll 3
    for (int kk = 0; kk < KK; kk++) {
        const int ky = kk / 3, kx = kk - ky * 3;
#pragma unroll
        for (int ks = 0; ks < 2; ks++) {
            const bf16x8* wa = (const bf16x8*)woA + (size_t)((kk * 2 + ks) * 2) * 64;
            bf16x8 A0 = wa[lane];
            bf16x8 A1 = wa[64 + lane];
            bf16x8 B = *(const bf16x8*)&xs[(ky * 66 + wv * 16 + pxin + kx) * SP
                                           + ks * 32 + quad * 8];
            acc0 = __builtin_amdgcn_mfma_f32_16x16x32_bf16(A0, B, acc0, 0, 0, 0);
            acc1 = __builtin_amdgcn_mfma_f32_16x16x32_bf16(A1, B, acc1, 0, 0, 0);
        }
    }

    float* outp = off + ((size_t)b * NOFF * HH + h) * WW + w0 + wv * 16 + pxin;
#pragma unroll
    for (int r = 0; r < 4; r++) {
        int c0 = quad * 4 + r;
        outp[c0 * PLANE] = acc0[r];
        int c1 = 16 + quad * 4 + r;
        if (c1 < NOFF) outp[c1 * PLANE] = acc1[r];
    }
}

// ---------------- deform sample + MFMA main conv (R14) ----------------
// Barrier-free: each wave owns a 16-px tile and gathers ALL 64 channels for
// its own MFMA B-fragments directly into registers (lane l: px = wtile*16 +
// (l&15), ci = ks*32 + (l>>4)*8 + j) -- the LDS exchange and its per-kk
// lockstep barrier are gone. Waves slip independently; vmcnt pipelining and
// unroll-3 hide gather latency. Full kk 0..8 per block (grid 1024, no split),
// which enables fused per-block channel stats (shfl butterfly + 2KB LDS
// reduce + non-atomic 512KB partial array; NO global atomics -- R12 lesson).
__global__ __launch_bounds__(256, 3) void deform_kernel(const float* __restrict__ x,
                                                        const unsigned short* __restrict__ w_bf,
                                                        const float* __restrict__ off,
                                                        const float* __restrict__ b_off,
                                                        float* __restrict__ out,
                                                        float* __restrict__ pstats) {
    const int id    = blockIdx.x;              // 0..1023
    const int slot  = id & 7;
    const int b     = slot >> 1;
    const int rb    = id >> 3;                 // 0..127
    const int h     = (slot & 1) * 64 + (rb >> 1);
    const int whalf = rb & 1;
    const int tid   = threadIdx.x;
    const int lane  = tid & 63;
    const int wave  = __builtin_amdgcn_readfirstlane(tid >> 6);
    const int quad  = lane >> 4, pxin = lane & 15;

    f32x4 acc[4];
#pragma unroll
    for (int t = 0; t < 4; t++) acc[t] = (f32x4){0.f, 0.f, 0.f, 0.f};

    const int wpix = whalf * 64 + wave * 16 + pxin;       // this lane's pixel
    const float* xb0  = x + ((size_t)b * CHI + quad * 8) * PLANE;   // ks=0 base
    const float* offb = off + (size_t)b * NOFF * PLANE + h * WW + wpix;

    // prefetch offsets for kk=0
    float dyv = offb[0 * PLANE]  + b_off[0];
    float dxv = offb[1 * PLANE]  + b_off[1];
    float mov = offb[18 * PLANE] + b_off[18];

#pragma unroll 3
    for (int kk = 0; kk < KK; kk++) {
        const int ky = kk / 3, kx = kk - ky * 3;
        // ---- bilinear params for this lane's pixel ----
        float m   = 1.f / (1.f + __expf(-mov));
        float py  = (float)(h - 1 + ky) + dyv;
        float px_ = (float)(wpix - 1 + kx) + dxv;
        float fy0 = floorf(py), fx0 = floorf(px_);
        float wy = py - fy0, wx = px_ - fx0;
        int y0 = (int)fy0, x0 = (int)fx0;
        int y1 = y0 + 1, x1 = x0 + 1;
        bool vy0 = (unsigned)y0 < HH, vy1 = (unsigned)y1 < HH;
        bool vx0 = (unsigned)x0 < WW, vx1 = (unsigned)x1 < WW;
        float a00 = (vy0 && vx0) ? (1.f - wy) * (1.f - wx) * m : 0.f;
        float a01 = (vy0 && vx1) ? (1.f - wy) * wx * m : 0.f;
        float a10 = (vy1 && vx0) ? wy * (1.f - wx) * m : 0.f;
        float a11 = (vy1 && vx1) ? wy * wx * m : 0.f;
        int xbc = min(max(x0, 0), WW - 2);
        bool sel = (x0 == xbc);
        v2f cA = { sel ? a00 : a01, sel ? a01 : a00 };
        v2f cB = { sel ? a10 : a11, sel ? a11 : a10 };
        int cy0 = min(max(y0, 0), HH - 1), cy1 = min(max(y1, 0), HH - 1);
        const unsigned o0 = (unsigned)(cy0 * WW + xbc);
        const unsigned o1 = (unsigned)(cy1 * WW + xbc);

        // ---- gather 64 channels for this pixel (16 j-slots x 2 rows) ----
        f2v p0[16], p1[16];
        {
            const float* pl = xb0;
#pragma unroll
            for (int j = 0; j < 8; j++) {
                p0[j] = *(const f2v*)(pl + o0);
                p1[j] = *(const f2v*)(pl + o1);
                pl += PLANE;
            }
            pl = xb0 + 32 * PLANE;             // ks=1 channel block
#pragma unroll
            for (int j = 8; j < 16; j++) {
                p0[j] = *(const f2v*)(pl + o0);
                p1[j] = *(const f2v*)(pl + o1);
                pl += PLANE;
            }
        }

        // prefetch offsets for kk+1 (hides under combine+MFMA)
        if (kk + 1 < KK) {
            dyv = offb[(2 * kk + 2) * PLANE]  + b_off[2 * kk + 2];
            dxv = offb[(2 * kk + 3) * PLANE]  + b_off[2 * kk + 3];
            mov = offb[(18 + kk + 1) * PLANE] + b_off[18 + kk + 1];
        }

        // ---- A fragments for all 4 co-tiles x 2 ks (L2-hot table) ----
        const bf16x8* wb = (const bf16x8*)w_bf + (size_t)(kk * 8) * 64;
        bf16x8 A[8];
#pragma unroll
        for (int q = 0; q < 8; q++) A[q] = wb[q * 64 + lane];

        // ---- combine to B fragments in-register ----
        bf16x8 B0, B1;
#pragma unroll
        for (int j = 0; j < 8; j++) {
            v2f t0 = pkfma((v2f)p1[j], cB, (v2f)p0[j] * cA);
            B0[j] = (short)f2bf(t0.x + t0.y);
            v2f t1 = pkfma((v2f)p1[8 + j], cB, (v2f)p0[8 + j] * cA);
            B1[j] = (short)f2bf(t1.x + t1.y);
        }

        // ---- 8 MFMAs: all co-tiles, both ks halves ----
#pragma unroll
        for (int t = 0; t < 4; t++) {
            acc[t] = __builtin_amdgcn_mfma_f32_16x16x32_bf16(A[t * 2 + 0], B0, acc[t], 0, 0, 0);
            acc[t] = __builtin_amdgcn_mfma_f32_16x16x32_bf16(A[t * 2 + 1], B1, acc[t], 0, 0, 0);
        }
    }

    // ---- output write: px = wave*16 + pxin, co = t*16 + quad*4 + r ----
#pragma unroll
    for (int t = 0; t < 4; t++) {
#pragma unroll
        for (int r = 0; r < 4; r++) {
            int co = t * 16 + quad * 4 + r;
            out[(((size_t)b * CHO + co) * HH + h) * WW + whalf * 64 + wave * 16 + pxin] =
                acc[t][r];
        }
    }

    // ---- fused per-block channel stats (sum, sum^2 over this block's 64 px) ----
    __shared__ float red[2][4][64];            // [s|s2][wave][co], 2 KB
#pragma unroll
    for (int t = 0; t < 4; t++) {
#pragma unroll
        for (int r = 0; r < 4; r++) {
            float s  = acc[t][r];
            float s2 = s * s;
#pragma unroll
            for (int mk = 1; mk < 16; mk <<= 1) {
                s  += __shfl_xor(s, mk, 64);
                s2 += __shfl_xor(s2, mk, 64);
            }
            if (pxin == 0) {
                int co = t * 16 + quad * 4 + r;
                red[0][wave][co] = s;
                red[1][wave][co] = s2;
            }
        }
    }
    __syncthreads();
    if (tid < 128) {
        int part = tid >> 6, idx = tid & 63;
        float v = red[part][0][idx] + red[part][1][idx]
                + red[part][2][idx] + red[part][3][idx];
        pstats[(size_t)(part * 64 + idx) * 1024 + id] = v;   // transposed: coalesced reduce
    }
}

// ---------------- final stats reduce: 1024 partials per channel ----------------
__global__ __launch_bounds__(256) void reduce_kernel(const float* __restrict__ pstats,
                                                     const float* __restrict__ bias,
                                                     float* __restrict__ stats) {
    const int co = blockIdx.x;                 // 0..63
    const float* ps  = pstats + (size_t)co * 1024;
    const float* ps2 = pstats + (size_t)(64 + co) * 1024;
    float s = 0.f, s2 = 0.f;
    for (int i = threadIdx.x; i < 1024; i += 256) {
        s  += ps[i];
        s2 += ps2[i];
    }
#pragma unroll
    for (int o = 32; o > 0; o >>= 1) {
        s  += __shfl_down(s, o, 64);
        s2 += __shfl_down(s2, o, 64);
    }
    __shared__ float ls[8];
    int lane = threadIdx.x & 63, wv = threadIdx.x >> 6;
    if (lane == 0) { ls[wv] = s; ls[4 + wv] = s2; }
    __syncthreads();
    if (threadIdx.x == 0) {
        float S = ls[0] + ls[1] + ls[2] + ls[3];
        float S2 = ls[4] + ls[5] + ls[6] + ls[7];
        float bi = bias[co];
        // fold bias analytically: sum(v+b) , sum((v+b)^2)
        stats[co]      = S + 65536.f * bi;
        stats[64 + co] = S2 + 2.f * bi * S + 65536.f * bi * bi;
    }
}

// ---------------- BN + ReLU ----------------
__global__ __launch_bounds__(256) void bn_kernel(float* __restrict__ y,
                                                 const float* __restrict__ bias,
                                                 const float* __restrict__ stats,
                                                 const float* __restrict__ gamma,
                                                 const float* __restrict__ beta) {
    size_t base = (size_t)blockIdx.x * 1024;
    int co = (int)((base >> 14) & 63);
    const float inv_n = 1.f / 65536.f;
    float mean = stats[co] * inv_n;
    float var  = stats[64 + co] * inv_n - mean * mean;
    float sc = gamma[co] * rsqrtf(var + EPSV);
    float sh = beta[co] - mean * sc;
    sh += bias[co] * sc;                       // y stored raw; fold bias into shift
    float4* p = (float4*)(y + base);
    float4 v = p[threadIdx.x];
    v.x = fmaxf(fmaf(v.x, sc, sh), 0.f);
    v.y = fmaxf(fmaf(v.y, sc, sh), 0.f);
    v.z = fmaxf(fmaf(v.z, sc, sh), 0.f);
    v.w = fmaxf(fmaf(v.w, sc, sh), 0.f);
    p[threadIdx.x] = v;
}

extern "C" void kernel_launch(void* const* d_in, const int* in_sizes, int n_in,
                              void* d_out, int out_size, void* d_ws, size_t ws_size,
                              hipStream_t stream) {
    const float* x     = (const float*)d_in[0];
    const float* w_off = (const float*)d_in[1];
    const float* b_off = (const float*)d_in[2];
    const float* wmat  = (const float*)d_in[3];
    const float* bvec  = (const float*)d_in[4];
    const float* gamma = (const float*)d_in[5];
    const float* beta  = (const float*)d_in[6];
    float* out = (float*)d_out;

    char* ws = (char*)d_ws;
    float* stats          = (float*)ws;                   // 512 B
    unsigned short* w_bf  = (unsigned short*)(ws + 1024); // 73728 B
    unsigned short* woA   = (unsigned short*)(ws + 74752);// 36864 B
    float* off            = (float*)(ws + 139264);        // 7077888 B
    float* pstats         = (float*)(ws + 7217152);       // 524288 B

    prep_kernel<<<144, 256, 0, stream>>>(wmat, w_off, w_bf, woA);
    off_conv_kernel<<<1024, 256, 0, stream>>>(x, woA, off);
    deform_kernel<<<1024, 256, 0, stream>>>(x, w_bf, off, b_off, out, pstats);
    reduce_kernel<<<64, 256, 0, stream>>>(pstats, bvec, stats);
    bn_kernel<<<4096, 256, 0, stream>>>(out, bvec, stats, gamma, beta);
}

// Round 3
// 146.406 us; speedup vs baseline: 1.2661x; 1.1947x over previous
//
#include <hip/hip_runtime.h>
#include <math.h>

#define CHI 64
#define CHO 64
#define HH 128
#define WW 128
#define NB 4
#define KK 9
#define NOFF 27
#define EPSV 1e-5f
#define PLANE (HH * WW)
#define SP 72                 // LDS ci-stride (shorts): 144B rows, 16B-aligned cells

typedef float f32x4 __attribute__((ext_vector_type(4)));
typedef short bf16x8 __attribute__((ext_vector_type(8)));
typedef unsigned int u32x4 __attribute__((ext_vector_type(4)));

// fp32 -> bf16 round-to-nearest-even
__device__ __forceinline__ unsigned short f2bf(float f) {
    unsigned u = __float_as_uint(f);
    u += 0x7fff + ((u >> 16) & 1);
    return (unsigned short)(u >> 16);
}
__device__ __forceinline__ float bfl(unsigned u) { return __uint_as_float(u << 16); }
__device__ __forceinline__ float bfh(unsigned u) { return __uint_as_float(u & 0xffff0000u); }

// ---------------- transpose: x[b][ci][y][x] fp32 -> x_bf[b][y][x][ci] bf16 ----
// grid 512 = (b,y). Coalesced read, LDS bounce, coalesced 16B write.
__global__ __launch_bounds__(256) void transpose_kernel(const float* __restrict__ x,
                                                        unsigned short* __restrict__ x_bf) {
    const int id = blockIdx.x;                 // b*128 + y
    const int b  = id >> 7;
    const int y  = id & 127;
    const int t  = threadIdx.x;
    __shared__ unsigned short lt[128 * SP];    // 18432 B

    const int ci = t >> 2, qx = t & 3;
    const float* src = x + ((size_t)(b * CHI + ci)) * PLANE + y * WW;
#pragma unroll
    for (int it = 0; it < 8; it++) {
        int xcol = (it * 4 + qx) * 4;
        float4 v = *(const float4*)(src + xcol);
        lt[(xcol + 0) * SP + ci] = f2bf(v.x);
        lt[(xcol + 1) * SP + ci] = f2bf(v.y);
        lt[(xcol + 2) * SP + ci] = f2bf(v.z);
        lt[(xcol + 3) * SP + ci] = f2bf(v.w);
    }
    __syncthreads();
    unsigned short* dst = x_bf + (size_t)id * (WW * 64);
#pragma unroll
    for (int it = 0; it < 4; it++) {
        int px  = it * 32 + (t >> 3);
        int ci8 = t & 7;
        u32x4 v = *(const u32x4*)&lt[px * SP + ci8 * 8];
        *(u32x4*)(dst + px * 64 + ci8 * 8) = v;
    }
}

// ---------------- prep: pack MFMA A-fragment tables (bf16) ----------------
__global__ __launch_bounds__(256) void prep_kernel(const float* __restrict__ w,
                                                   const float* __restrict__ w_off,
                                                   unsigned short* __restrict__ w_bf,
                                                   unsigned short* __restrict__ woA) {
    int i = blockIdx.x * 256 + threadIdx.x;    // grid 144*256 = 36864 exactly
    {
        int j    = i & 7;
        int lane = (i >> 3) & 63;
        int ks   = (i >> 9) & 1;
        int ct   = (i >> 10) & 3;
        int kk   = i >> 12;                    // 0..8
        int co   = ct * 16 + (lane & 15);
        int ci   = ks * 32 + ((lane >> 4) & 3) * 8 + j;
        w_bf[i]  = f2bf(w[(co * CHI + ci) * KK + kk]);
    }
    if (i < 18432) {
        int j    = i & 7;
        int lane = (i >> 3) & 63;
        int ct   = (i >> 9) & 1;
        int ks   = (i >> 10) & 1;
        int kk   = i >> 11;                    // 0..8
        int c    = ct * 16 + (lane & 15);
        int ci   = ks * 32 + (lane >> 4) * 8 + j;
        woA[i]   = (c < NOFF) ? f2bf(w_off[(c * CHI + ci) * KK + kk]) : (unsigned short)0;
    }
}

// ---------------- offset conv via MFMA (staging now from x_bf) ----------------
__global__ __launch_bounds__(256) void off_conv_kernel(const unsigned short* __restrict__ x_bf,
                                                       const unsigned short* __restrict__ woA,
                                                       float* __restrict__ off) {
    const int id    = blockIdx.x;
    const int slot  = id & 7;
    const int b     = slot >> 1;
    const int rb    = id >> 3;                 // 0..127
    const int h     = (slot & 1) * 64 + (rb >> 1);
    const int whalf = rb & 1;
    const int w0    = whalf * 64;
    const int tid   = threadIdx.x;
    const int lane  = tid & 63;
    const int wv    = __builtin_amdgcn_readfirstlane(tid >> 6);

    __shared__ __align__(16) unsigned short xs[3 * 66 * SP];     // 28512 B

    const unsigned short* xb = x_bf + (size_t)b * (PLANE * 64);
#pragma unroll
    for (int ky = 0; ky < 3; ky++) {
        int hr = h - 1 + ky;
        for (int base = tid; base < 528; base += 256) {          // 66 cols x 8 ci-blocks
            int col = base >> 3, ci8 = base & 7;
            int wc  = w0 - 1 + col;
            bool ok = ((unsigned)hr < HH) && ((unsigned)wc < WW);
            u32x4 v = {0u, 0u, 0u, 0u};
            if (ok) v = *(const u32x4*)(xb + ((size_t)(hr * WW + wc)) * 64 + ci8 * 8);
            *(u32x4*)&xs[(ky * 66 + col) * SP + ci8 * 8] = v;
        }
    }
    __syncthreads();

    const int quad = lane >> 4, pxin = lane & 15;
    f32x4 acc0 = {0.f, 0.f, 0.f, 0.f};
    f32x4 acc1 = {0.f, 0.f, 0.f, 0.f};

#pragma unroll 3
    for (int kk = 0; kk < KK; kk++) {
        const int ky = kk / 3, kx = kk - ky * 3;
#pragma unroll
        for (int ks = 0; ks < 2; ks++) {
            const bf16x8* wa = (const bf16x8*)woA + (size_t)((kk * 2 + ks) * 2) * 64;
            bf16x8 A0 = wa[lane];
            bf16x8 A1 = wa[64 + lane];
            bf16x8 B = *(const bf16x8*)&xs[(ky * 66 + wv * 16 + pxin + kx) * SP
                                           + ks * 32 + quad * 8];
            acc0 = __builtin_amdgcn_mfma_f32_16x16x32_bf16(A0, B, acc0, 0, 0, 0);
            acc1 = __builtin_amdgcn_mfma_f32_16x16x32_bf16(A1, B, acc1, 0, 0, 0);
        }
    }

    float* outp = off + ((size_t)b * NOFF * HH + h) * WW + w0 + wv * 16 + pxin;
#pragma unroll
    for (int r = 0; r < 4; r++) {
        int c0 = quad * 4 + r;
        outp[c0 * PLANE] = acc0[r];
        int c1 = 16 + quad * 4 + r;
        if (c1 < NOFF) outp[c1 * PLANE] = acc1[r];
    }
}

// ---------------- deform sample + MFMA main conv (R15) ----------------
// Channels-last bf16 gather: lane(quad,pxin) loads its 8-ci B-slice as ONE
// dwordx4 per corner (8 loads/kk vs 32) -- dense 64B-line utilization kills
// the TA transaction storm that R13/R14 showed was the wall. Barrier-free,
// fused block stats (non-atomic partials).
__global__ __launch_bounds__(256, 3) void deform_kernel(const unsigned short* __restrict__ x_bf,
                                                        const unsigned short* __restrict__ w_bf,
                                                        const float* __restrict__ off,
                                                        const float* __restrict__ b_off,
                                                        float* __restrict__ out,
                                                        float* __restrict__ pstats) {
    const int id    = blockIdx.x;              // 0..1023
    const int slot  = id & 7;
    const int b     = slot >> 1;
    const int rb    = id >> 3;                 // 0..127
    const int h     = (slot & 1) * 64 + (rb >> 1);
    const int whalf = rb & 1;
    const int tid   = threadIdx.x;
    const int lane  = tid & 63;
    const int wave  = __builtin_amdgcn_readfirstlane(tid >> 6);
    const int quad  = lane >> 4, pxin = lane & 15;

    f32x4 acc[4];
#pragma unroll
    for (int t = 0; t < 4; t++) acc[t] = (f32x4){0.f, 0.f, 0.f, 0.f};

    const int wpix = whalf * 64 + wave * 16 + pxin;       // this lane's pixel
    const unsigned short* xbq = x_bf + (size_t)b * (PLANE * 64) + quad * 8;
    const float* offb = off + (size_t)b * NOFF * PLANE + h * WW + wpix;

    // prefetch offsets for kk=0
    float dyv = offb[0 * PLANE]  + b_off[0];
    float dxv = offb[1 * PLANE]  + b_off[1];
    float mov = offb[18 * PLANE] + b_off[18];

#pragma unroll 3
    for (int kk = 0; kk < KK; kk++) {
        const int ky = kk / 3, kx = kk - ky * 3;
        // ---- bilinear params for this lane's pixel ----
        float m   = 1.f / (1.f + __expf(-mov));
        float py  = (float)(h - 1 + ky) + dyv;
        float px_ = (float)(wpix - 1 + kx) + dxv;
        float fy0 = floorf(py), fx0 = floorf(px_);
        float wy = py - fy0, wx = px_ - fx0;
        int y0 = (int)fy0, x0 = (int)fx0;
        int y1 = y0 + 1, x1 = x0 + 1;
        bool vy0 = (unsigned)y0 < HH, vy1 = (unsigned)y1 < HH;
        bool vx0 = (unsigned)x0 < WW, vx1 = (unsigned)x1 < WW;
        float a00 = (vy0 && vx0) ? (1.f - wy) * (1.f - wx) * m : 0.f;
        float a01 = (vy0 && vx1) ? (1.f - wy) * wx * m : 0.f;
        float a10 = (vy1 && vx0) ? wy * (1.f - wx) * m : 0.f;
        float a11 = (vy1 && vx1) ? wy * wx * m : 0.f;
        int cy0 = min(max(y0, 0), HH - 1), cy1 = min(max(y1, 0), HH - 1);
        int cx0 = min(max(x0, 0), WW - 1), cx1 = min(max(x1, 0), WW - 1);
        const unsigned o00 = ((unsigned)(cy0 * WW + cx0)) << 6;
        const unsigned o01 = ((unsigned)(cy0 * WW + cx1)) << 6;
        const unsigned o10 = ((unsigned)(cy1 * WW + cx0)) << 6;
        const unsigned o11 = ((unsigned)(cy1 * WW + cx1)) << 6;

        // ---- 8 dense 16B gathers: 4 corners x 2 ks-halves ----
        u32x4 g00a = *(const u32x4*)(xbq + o00);
        u32x4 g01a = *(const u32x4*)(xbq + o01);
        u32x4 g10a = *(const u32x4*)(xbq + o10);
        u32x4 g11a = *(const u32x4*)(xbq + o11);
        u32x4 g00b = *(const u32x4*)(xbq + o00 + 32);
        u32x4 g01b = *(const u32x4*)(xbq + o01 + 32);
        u32x4 g10b = *(const u32x4*)(xbq + o10 + 32);
        u32x4 g11b = *(const u32x4*)(xbq + o11 + 32);

        // prefetch offsets for kk+1 (hides under combine+MFMA)
        if (kk + 1 < KK) {
            dyv = offb[(2 * kk + 2) * PLANE]  + b_off[2 * kk + 2];
            dxv = offb[(2 * kk + 3) * PLANE]  + b_off[2 * kk + 3];
            mov = offb[(18 + kk + 1) * PLANE] + b_off[18 + kk + 1];
        }

        // ---- A fragments for all 4 co-tiles x 2 ks (L2-hot table) ----
        const bf16x8* wb = (const bf16x8*)w_bf + (size_t)(kk * 8) * 64;
        bf16x8 A[8];
#pragma unroll
        for (int q = 0; q < 8; q++) A[q] = wb[q * 64 + lane];

        // ---- bilinear combine in fp32, round to bf16 B fragments ----
        bf16x8 B0, B1;
#pragma unroll
        for (int d = 0; d < 4; d++) {
            float tl = a00 * bfl(g00a[d]) + a01 * bfl(g01a[d])
                     + a10 * bfl(g10a[d]) + a11 * bfl(g11a[d]);
            float th = a00 * bfh(g00a[d]) + a01 * bfh(g01a[d])
                     + a10 * bfh(g10a[d]) + a11 * bfh(g11a[d]);
            B0[2 * d]     = (short)f2bf(tl);
            B0[2 * d + 1] = (short)f2bf(th);
            float ul = a00 * bfl(g00b[d]) + a01 * bfl(g01b[d])
                     + a10 * bfl(g10b[d]) + a11 * bfl(g11b[d]);
            float uh = a00 * bfh(g00b[d]) + a01 * bfh(g01b[d])
                     + a10 * bfh(g10b[d]) + a11 * bfh(g11b[d]);
            B1[2 * d]     = (short)f2bf(ul);
            B1[2 * d + 1] = (short)f2bf(uh);
        }

        // ---- 8 MFMAs: all co-tiles, both ks halves ----
#pragma unroll
        for (int t = 0; t < 4; t++) {
            acc[t] = __builtin_amdgcn_mfma_f32_16x16x32_bf16(A[t * 2 + 0], B0, acc[t], 0, 0, 0);
            acc[t] = __builtin_amdgcn_mfma_f32_16x16x32_bf16(A[t * 2 + 1], B1, acc[t], 0, 0, 0);
        }
    }

    // ---- output write: px = wave*16 + pxin, co = t*16 + quad*4 + r ----
#pragma unroll
    for (int t = 0; t < 4; t++) {
#pragma unroll
        for (int r = 0; r < 4; r++) {
            int co = t * 16 + quad * 4 + r;
            out[(((size_t)b * CHO + co) * HH + h) * WW + whalf * 64 + wave * 16 + pxin] =
                acc[t][r];
        }
    }

    // ---- fused per-block channel stats (sum, sum^2 over this block's 64 px) ----
    __shared__ float red[2][4][64];            // [s|s2][wave][co], 2 KB
#pragma unroll
    for (int t = 0; t < 4; t++) {
#pragma unroll
        for (int r = 0; r < 4; r++) {
            float s  = acc[t][r];
            float s2 = s * s;
#pragma unroll
            for (int mk = 1; mk < 16; mk <<= 1) {
                s  += __shfl_xor(s, mk, 64);
                s2 += __shfl_xor(s2, mk, 64);
            }
            if (pxin == 0) {
                int co = t * 16 + quad * 4 + r;
                red[0][wave][co] = s;
                red[1][wave][co] = s2;
            }
        }
    }
    __syncthreads();
    if (tid < 128) {
        int part = tid >> 6, idx = tid & 63;
        float v = red[part][0][idx] + red[part][1][idx]
                + red[part][2][idx] + red[part][3][idx];
        pstats[(size_t)(part * 64 + idx) * 1024 + id] = v;   // transposed: coalesced reduce
    }
}

// ---------------- final stats reduce: 1024 partials per channel ----------------
__global__ __launch_bounds__(256) void reduce_kernel(const float* __restrict__ pstats,
                                                     const float* __restrict__ bias,
                                                     float* __restrict__ stats) {
    const int co = blockIdx.x;                 // 0..63
    const float* ps  = pstats + (size_t)co * 1024;
    const float* ps2 = pstats + (size_t)(64 + co) * 1024;
    float s = 0.f, s2 = 0.f;
    for (int i = threadIdx.x; i < 1024; i += 256) {
        s  += ps[i];
        s2 += ps2[i];
    }
#pragma unroll
    for (int o = 32; o > 0; o >>= 1) {
        s  += __shfl_down(s, o, 64);
        s2 += __shfl_down(s2, o, 64);
    }
    __shared__ float ls[8];
    int lane = threadIdx.x & 63, wv = threadIdx.x >> 6;
    if (lane == 0) { ls[wv] = s; ls[4 + wv] = s2; }
    __syncthreads();
    if (threadIdx.x == 0) {
        float S = ls[0] + ls[1] + ls[2] + ls[3];
        float S2 = ls[4] + ls[5] + ls[6] + ls[7];
        float bi = bias[co];
        // fold bias analytically: sum(v+b) , sum((v+b)^2)
        stats[co]      = S + 65536.f * bi;
        stats[64 + co] = S2 + 2.f * bi * S + 65536.f * bi * bi;
    }
}

// ---------------- BN + ReLU ----------------
__global__ __launch_bounds__(256) void bn_kernel(float* __restrict__ y,
                                                 const float* __restrict__ bias,
                                                 const float* __restrict__ stats,
                                                 const float* __restrict__ gamma,
                                                 const float* __restrict__ beta) {
    size_t base = (size_t)blockIdx.x * 1024;
    int co = (int)((base >> 14) & 63);
    const float inv_n = 1.f / 65536.f;
    float mean = stats[co] * inv_n;
    float var  = stats[64 + co] * inv_n - mean * mean;
    float sc = gamma[co] * rsqrtf(var + EPSV);
    float sh = beta[co] - mean * sc;
    sh += bias[co] * sc;                       // y stored raw; fold bias into shift
    float4* p = (float4*)(y + base);
    float4 v = p[threadIdx.x];
    v.x = fmaxf(fmaf(v.x, sc, sh), 0.f);
    v.y = fmaxf(fmaf(v.y, sc, sh), 0.f);
    v.z = fmaxf(fmaf(v.z, sc, sh), 0.f);
    v.w = fmaxf(fmaf(v.w, sc, sh), 0.f);
    p[threadIdx.x] = v;
}

extern "C" void kernel_launch(void* const* d_in, const int* in_sizes, int n_in,
                              void* d_out, int out_size, void* d_ws, size_t ws_size,
                              hipStream_t stream) {
    const float* x     = (const float*)d_in[0];
    const float* w_off = (const float*)d_in[1];
    const float* b_off = (const float*)d_in[2];
    const float* wmat  = (const float*)d_in[3];
    const float* bvec  = (const float*)d_in[4];
    const float* gamma = (const float*)d_in[5];
    const float* beta  = (const float*)d_in[6];
    float* out = (float*)d_out;

    char* ws = (char*)d_ws;
    float* stats          = (float*)ws;                     // 512 B
    unsigned short* w_bf  = (unsigned short*)(ws + 1024);   // 73728 B
    unsigned short* woA   = (unsigned short*)(ws + 74752);  // 36864 B
    float* off            = (float*)(ws + 139264);          // 7077888 B
    unsigned short* x_bf  = (unsigned short*)(ws + 7217152);// 8388608 B
    float* pstats         = (float*)(ws + 15605760);        // 524288 B -> 16130048 total

    transpose_kernel<<<512, 256, 0, stream>>>(x, x_bf);
    prep_kernel<<<144, 256, 0, stream>>>(wmat, w_off, w_bf, woA);
    off_conv_kernel<<<1024, 256, 0, stream>>>(x_bf, woA, off);
    deform_kernel<<<1024, 256, 0, stream>>>(x_bf, w_bf, off, b_off, out, pstats);
    reduce_kernel<<<64, 256, 0, stream>>>(pstats, bvec, stats);
    bn_kernel<<<4096, 256, 0, stream>>>(out, bvec, stats, gamma, beta);
}